// Round 6
// baseline (706.913 us; speedup 1.0000x reference)
//
#include <hip/hip_runtime.h>

#define N_G   15135
#define E_N   242160
#define BSZ   8
#define K_TOP 7568
#define NH    128

// ---------------- utility ----------------
__global__ void zero_kernel(int* __restrict__ p, int n) {
  int i = blockIdx.x * 1024 + threadIdx.x;
  if (i < n) p[i] = 0;
}

__global__ void count_kernel(const int* __restrict__ ei, int* __restrict__ cnt) {
  int e = blockIdx.x * 256 + threadIdx.x;
  if (e < E_N) atomicAdd(&cnt[ei[E_N + e]], 1);
}

// per-chunk local scan + atomic ticket for block base; also dinv and 1/||topk_w||.
__global__ __launch_bounds__(1024) void scan_kernel(const int* __restrict__ cnt,
                                                    int* __restrict__ rowstart,
                                                    float* __restrict__ dinv,
                                                    int* __restrict__ gctr,
                                                    const float* __restrict__ topk_w,
                                                    float* __restrict__ scal) {
  __shared__ int buf[1024];
  __shared__ int base;
  int tid = threadIdx.x;
  int i = blockIdx.x * 1024 + tid;
  int v = (i < N_G) ? cnt[i] : 0;
  if (i < N_G) dinv[i] = 1.0f / sqrtf((float)(v + 1));  // +1 = self loop
  buf[tid] = v;
  __syncthreads();
  for (int s = 1; s < 1024; s <<= 1) {
    int t = (tid >= s) ? buf[tid - s] : 0;
    __syncthreads();
    buf[tid] += t;
    __syncthreads();
  }
  if (tid == 1023) base = atomicAdd(gctr, buf[1023]);
  __syncthreads();
  if (i < N_G) rowstart[i] = base + buf[tid] - v;
  if (blockIdx.x == 0) {
    __shared__ float fbuf[512];
    if (tid < 512) {
      float w = (tid < 384) ? topk_w[tid] : 0.f;
      fbuf[tid] = w * w;
    }
    __syncthreads();
    for (int s = 256; s > 0; s >>= 1) {
      if (tid < s) fbuf[tid] += fbuf[tid + s];
      __syncthreads();
    }
    if (tid == 0) scal[0] = 1.0f / sqrtf(fbuf[0]);
  }
}

__global__ void fill_kernel(const int* __restrict__ ei, const int* __restrict__ rowstart,
                            const float* __restrict__ dinv, int* __restrict__ fillc,
                            int2* __restrict__ csr) {
  int e = blockIdx.x * 256 + threadIdx.x;
  if (e < E_N) {
    int s = ei[e], d = ei[E_N + e];
    int pos = rowstart[d] + atomicAdd(&fillc[d], 1);
    csr[pos] = make_int2(s, __float_as_int(dinv[s]));
  }
}

// ---------------- dense matmul: out[M][128] = A[M][CIN] @ W[CIN][128] ----------------
// BM=64, BN=128, BK=32; 256 threads, 8x4 frag. LDS 25.6 KB -> 6 blocks/CU.
template<int CIN>
__global__ __launch_bounds__(256, 6) void mm_kernel(const float* __restrict__ A,
                                                    const float* __restrict__ W,
                                                    float* __restrict__ out, int M) {
  __shared__ float Bst[32][132];  // [kk][col]
  __shared__ float Ast2[32][68];  // [kk][row]
  int tid = threadIdx.x;
  int rb0 = blockIdx.x * 64;
  int c0 = (tid & 31) * 4;
  int r0 = (tid >> 5) * 8;
  float acc[8][4];
#pragma unroll
  for (int i = 0; i < 8; i++)
#pragma unroll
    for (int j = 0; j < 4; j++) acc[i][j] = 0.f;

  for (int k0 = 0; k0 < CIN; k0 += 32) {
    {
      int koff = (tid & 7) * 4;
      int row = tid >> 3;  // 0..31
#pragma unroll
      for (int p = 0; p < 2; ++p) {
        int r = row + p * 32;
        int grow = rb0 + r;
        float4 v = make_float4(0.f, 0.f, 0.f, 0.f);
        if (grow < M) v = *(const float4*)(A + (size_t)grow * CIN + k0 + koff);
        Ast2[koff + 0][r] = v.x; Ast2[koff + 1][r] = v.y;
        Ast2[koff + 2][r] = v.z; Ast2[koff + 3][r] = v.w;
      }
    }
    {
      int cc = (tid & 31) * 4;
      int kr = tid >> 5;  // 0..7
#pragma unroll
      for (int p = 0; p < 4; ++p) {
        int k = kr + p * 8;
        *(float4*)&Bst[k][cc] = *(const float4*)(W + (size_t)(k0 + k) * NH + cc);
      }
    }
    __syncthreads();
#pragma unroll 4
    for (int kk = 0; kk < 32; ++kk) {
      float a[8], b[4];
      *(float4*)&a[0] = *(const float4*)&Ast2[kk][r0];
      *(float4*)&a[4] = *(const float4*)&Ast2[kk][r0 + 4];
      *(float4*)&b[0] = *(const float4*)&Bst[kk][c0];
#pragma unroll
      for (int i = 0; i < 8; i++)
#pragma unroll
        for (int j = 0; j < 4; j++)
          acc[i][j] = fmaf(a[i], b[j], acc[i][j]);
    }
    __syncthreads();
  }
#pragma unroll
  for (int i = 0; i < 8; i++) {
    int row = rb0 + r0 + i;
    if (row < M)
      *(float4*)(out + (size_t)row * NH + c0) = make_float4(acc[i][0], acc[i][1], acc[i][2], acc[i][3]);
  }
}

// ---------------- sparse aggregation + bias + relu ----------------
// One wave per dest. Edge metadata via uniform (readfirstlane) scalar loads ->
// SGPR src/weight, gathers are SGPR-base + lane offset, 8-deep MLP.
__global__ __launch_bounds__(256) void agg_kernel(const float* __restrict__ hw,
                                                  const int2* __restrict__ csr,
                                                  const int* __restrict__ rowstart,
                                                  const int* __restrict__ cnt,
                                                  const float* __restrict__ dinv,
                                                  const float* __restrict__ bias,
                                                  float* __restrict__ hout) {
  int b = blockIdx.x & 7;
  int chunk = blockIdx.x >> 3;
  int wave = threadIdx.x >> 6, lane = threadIdx.x & 63;
  int d = chunk * 4 + wave;
  if (d >= N_G) return;
  d = __builtin_amdgcn_readfirstlane(d);
  const float2* hwb = (const float2*)(hw + (size_t)b * N_G * NH);
  float dv = dinv[d];
  int e0 = rowstart[d];
  int n = cnt[d];
  const int2* ce = csr + e0;
  float2 vd = hwb[(size_t)d * 64 + lane];
  float a0x = dv * vd.x, a0y = dv * vd.y;
  float a1x = 0.f, a1y = 0.f, a2x = 0.f, a2y = 0.f, a3x = 0.f, a3y = 0.f;
  int l = 0;
  for (; l + 8 <= n; l += 8) {
    int2 p0 = ce[l + 0], p1 = ce[l + 1], p2 = ce[l + 2], p3 = ce[l + 3];
    int2 p4 = ce[l + 4], p5 = ce[l + 5], p6 = ce[l + 6], p7 = ce[l + 7];
    float2 v0 = hwb[(size_t)p0.x * 64 + lane];
    float2 v1 = hwb[(size_t)p1.x * 64 + lane];
    float2 v2 = hwb[(size_t)p2.x * 64 + lane];
    float2 v3 = hwb[(size_t)p3.x * 64 + lane];
    float2 v4 = hwb[(size_t)p4.x * 64 + lane];
    float2 v5 = hwb[(size_t)p5.x * 64 + lane];
    float2 v6 = hwb[(size_t)p6.x * 64 + lane];
    float2 v7 = hwb[(size_t)p7.x * 64 + lane];
    a0x = fmaf(__int_as_float(p0.y), v0.x, a0x); a0y = fmaf(__int_as_float(p0.y), v0.y, a0y);
    a1x = fmaf(__int_as_float(p1.y), v1.x, a1x); a1y = fmaf(__int_as_float(p1.y), v1.y, a1y);
    a2x = fmaf(__int_as_float(p2.y), v2.x, a2x); a2y = fmaf(__int_as_float(p2.y), v2.y, a2y);
    a3x = fmaf(__int_as_float(p3.y), v3.x, a3x); a3y = fmaf(__int_as_float(p3.y), v3.y, a3y);
    a0x = fmaf(__int_as_float(p4.y), v4.x, a0x); a0y = fmaf(__int_as_float(p4.y), v4.y, a0y);
    a1x = fmaf(__int_as_float(p5.y), v5.x, a1x); a1y = fmaf(__int_as_float(p5.y), v5.y, a1y);
    a2x = fmaf(__int_as_float(p6.y), v6.x, a2x); a2y = fmaf(__int_as_float(p6.y), v6.y, a2y);
    a3x = fmaf(__int_as_float(p7.y), v7.x, a3x); a3y = fmaf(__int_as_float(p7.y), v7.y, a3y);
  }
  for (; l < n; ++l) {
    int2 p = ce[l];
    float2 v = hwb[(size_t)p.x * 64 + lane];
    a0x = fmaf(__int_as_float(p.y), v.x, a0x); a0y = fmaf(__int_as_float(p.y), v.y, a0y);
  }
  float sx = a0x + a1x + a2x + a3x;
  float sy = a0y + a1y + a2y + a3y;
  float2 bb = ((const float2*)bias)[lane];
  float2 r;
  r.x = fmaxf(fmaf(dv, sx, bb.x), 0.f);
  r.y = fmaxf(fmaf(dv, sy, bb.y), 0.f);
  ((float2*)hout)[((size_t)b * N_G + d) * 64 + lane] = r;
}

// ---------------- layer-3 aggregation fused with score/key/fc-dot (h3 never stored) ----
__global__ __launch_bounds__(256) void agg_score_kernel(const float* __restrict__ hw,
                                                        const int2* __restrict__ csr,
                                                        const int* __restrict__ rowstart,
                                                        const int* __restrict__ cnt,
                                                        const float* __restrict__ dinv,
                                                        const float* __restrict__ bias,
                                                        const float* __restrict__ h1,
                                                        const float* __restrict__ h2,
                                                        const float* __restrict__ topk_w,
                                                        const float* __restrict__ fcW,
                                                        const float* __restrict__ scal,
                                                        unsigned* __restrict__ keys,
                                                        float* __restrict__ score,
                                                        float* __restrict__ d2a) {
  int b = blockIdx.x & 7;
  int chunk = blockIdx.x >> 3;
  int wave = threadIdx.x >> 6, lane = threadIdx.x & 63;
  int d = chunk * 4 + wave;
  if (d >= N_G) return;
  d = __builtin_amdgcn_readfirstlane(d);
  const float2* hwb = (const float2*)(hw + (size_t)b * N_G * NH);
  float dv = dinv[d];
  int e0 = rowstart[d];
  int n = cnt[d];
  const int2* ce = csr + e0;
  float2 vd = hwb[(size_t)d * 64 + lane];
  float a0x = dv * vd.x, a0y = dv * vd.y;
  float a1x = 0.f, a1y = 0.f, a2x = 0.f, a2y = 0.f, a3x = 0.f, a3y = 0.f;
  int l = 0;
  for (; l + 8 <= n; l += 8) {
    int2 p0 = ce[l + 0], p1 = ce[l + 1], p2 = ce[l + 2], p3 = ce[l + 3];
    int2 p4 = ce[l + 4], p5 = ce[l + 5], p6 = ce[l + 6], p7 = ce[l + 7];
    float2 v0 = hwb[(size_t)p0.x * 64 + lane];
    float2 v1 = hwb[(size_t)p1.x * 64 + lane];
    float2 v2 = hwb[(size_t)p2.x * 64 + lane];
    float2 v3 = hwb[(size_t)p3.x * 64 + lane];
    float2 v4 = hwb[(size_t)p4.x * 64 + lane];
    float2 v5 = hwb[(size_t)p5.x * 64 + lane];
    float2 v6 = hwb[(size_t)p6.x * 64 + lane];
    float2 v7 = hwb[(size_t)p7.x * 64 + lane];
    a0x = fmaf(__int_as_float(p0.y), v0.x, a0x); a0y = fmaf(__int_as_float(p0.y), v0.y, a0y);
    a1x = fmaf(__int_as_float(p1.y), v1.x, a1x); a1y = fmaf(__int_as_float(p1.y), v1.y, a1y);
    a2x = fmaf(__int_as_float(p2.y), v2.x, a2x); a2y = fmaf(__int_as_float(p2.y), v2.y, a2y);
    a3x = fmaf(__int_as_float(p3.y), v3.x, a3x); a3y = fmaf(__int_as_float(p3.y), v3.y, a3y);
    a0x = fmaf(__int_as_float(p4.y), v4.x, a0x); a0y = fmaf(__int_as_float(p4.y), v4.y, a0y);
    a1x = fmaf(__int_as_float(p5.y), v5.x, a1x); a1y = fmaf(__int_as_float(p5.y), v5.y, a1y);
    a2x = fmaf(__int_as_float(p6.y), v6.x, a2x); a2y = fmaf(__int_as_float(p6.y), v6.y, a2y);
    a3x = fmaf(__int_as_float(p7.y), v7.x, a3x); a3y = fmaf(__int_as_float(p7.y), v7.y, a3y);
  }
  for (; l < n; ++l) {
    int2 p = ce[l];
    float2 v = hwb[(size_t)p.x * 64 + lane];
    a0x = fmaf(__int_as_float(p.y), v.x, a0x); a0y = fmaf(__int_as_float(p.y), v.y, a0y);
  }
  float sx = a0x + a1x + a2x + a3x;
  float sy = a0y + a1y + a2y + a3y;
  float2 bb = ((const float2*)bias)[lane];
  float2 r;
  r.x = fmaxf(fmaf(dv, sx, bb.x), 0.f);
  r.y = fmaxf(fmaf(dv, sy, bb.y), 0.f);
  // fused score: xc feature order f = h*3 + layer
  size_t rbase = ((size_t)b * N_G + d) * 64 + lane;
  float2 u1 = ((const float2*)h1)[rbase];
  float2 u2 = ((const float2*)h2)[rbase];
  const float2* tw2 = (const float2*)topk_w;
  const float2* fw2 = (const float2*)fcW;
  float2 ta = tw2[lane * 3 + 0], tb = tw2[lane * 3 + 1], tc = tw2[lane * 3 + 2];
  float2 fa = fw2[lane * 3 + 0], fb = fw2[lane * 3 + 1], fc = fw2[lane * 3 + 2];
  float d1 = u1.x * ta.x + u2.x * ta.y + r.x * tb.x
           + u1.y * tb.y + u2.y * tc.x + r.y * tc.y;
  float d2 = u1.x * fa.x + u2.x * fa.y + r.x * fb.x
           + u1.y * fb.y + u2.y * fc.x + r.y * fc.y;
#pragma unroll
  for (int s = 32; s > 0; s >>= 1) {
    d1 += __shfl_down(d1, s);
    d2 += __shfl_down(d2, s);
  }
  if (lane == 0) {
    int gw = b * N_G + d;
    float sc = tanhf(d1 * scal[0]);
    score[gw] = sc;
    d2a[gw] = d2;
    unsigned int u = __float_as_uint(sc);
    unsigned int k32 = (u & 0x80000000u) ? ~u : (u | 0x80000000u);  // monotone float->u32
    keys[gw] = k32;
  }
}

// ---------------- exact descending rank, 32-bit compares ----------------
// rank[i] = #{j<i: k_j >= k_i} + #{j>i: k_j > k_i}  (== stable descending rank).
// Fast u32 loops when j-chunk is fully below/above the i-window; u64 path on diagonal.
#define RANK_JS  32
#define RANK_JCH 473  // ceil(15135/32)
__global__ __launch_bounds__(256) void rank_kernel(const unsigned* __restrict__ keys,
                                                   int* __restrict__ rank) {
  int b = blockIdx.y;
  int ib = blockIdx.x >> 5;          // 0..7  i-blocks of 2048
  int js = blockIdx.x & (RANK_JS-1); // 0..31 j-splits
  const unsigned* kb = keys + (size_t)b * N_G;
  int tid = threadIdx.x;
  int i0 = ib * 2048 + tid;
  unsigned ki[8];
  int cnt[8];
#pragma unroll
  for (int t = 0; t < 8; t++) {
    int i = i0 + t * 256;
    ki[t] = (i < N_G) ? kb[i] : 0xFFFFFFFFu;
    cnt[t] = 0;
  }
  int j0 = js * RANK_JCH;
  int j1 = j0 + RANK_JCH; if (j1 > N_G) j1 = N_G;
  int iw_lo = ib * 2048;
  int iw_hi = iw_lo + 2048; if (iw_hi > N_G) iw_hi = N_G;

  if (j1 <= iw_lo) {
    // every j < every i: count k_j >= k_i
    int j = j0;
    for (; j + 8 <= j1; j += 8) {
      unsigned k0 = kb[j+0], k1 = kb[j+1], k2 = kb[j+2], k3 = kb[j+3];
      unsigned k4 = kb[j+4], k5 = kb[j+5], k6 = kb[j+6], k7 = kb[j+7];
#pragma unroll
      for (int t = 0; t < 8; t++) {
        cnt[t] += (k0 >= ki[t]); cnt[t] += (k1 >= ki[t]);
        cnt[t] += (k2 >= ki[t]); cnt[t] += (k3 >= ki[t]);
        cnt[t] += (k4 >= ki[t]); cnt[t] += (k5 >= ki[t]);
        cnt[t] += (k6 >= ki[t]); cnt[t] += (k7 >= ki[t]);
      }
    }
    for (; j < j1; ++j) {
      unsigned kj = kb[j];
#pragma unroll
      for (int t = 0; t < 8; t++) cnt[t] += (kj >= ki[t]);
    }
  } else if (j0 >= iw_hi) {
    // every j > every i: count k_j > k_i
    int j = j0;
    for (; j + 8 <= j1; j += 8) {
      unsigned k0 = kb[j+0], k1 = kb[j+1], k2 = kb[j+2], k3 = kb[j+3];
      unsigned k4 = kb[j+4], k5 = kb[j+5], k6 = kb[j+6], k7 = kb[j+7];
#pragma unroll
      for (int t = 0; t < 8; t++) {
        cnt[t] += (k0 > ki[t]); cnt[t] += (k1 > ki[t]);
        cnt[t] += (k2 > ki[t]); cnt[t] += (k3 > ki[t]);
        cnt[t] += (k4 > ki[t]); cnt[t] += (k5 > ki[t]);
        cnt[t] += (k6 > ki[t]); cnt[t] += (k7 > ki[t]);
      }
    }
    for (; j < j1; ++j) {
      unsigned kj = kb[j];
#pragma unroll
      for (int t = 0; t < 8; t++) cnt[t] += (kj > ki[t]);
    }
  } else {
    // diagonal: exact u64 keys (key = k32<<32 | (0xFFFFFFFF - idx))
    unsigned long long ki64[8];
#pragma unroll
    for (int t = 0; t < 8; t++) {
      int i = i0 + t * 256;
      ki64[t] = ((unsigned long long)ki[t] << 32) | (unsigned long long)(0xFFFFFFFFu - (unsigned)i);
    }
    for (int j = j0; j < j1; ++j) {
      unsigned long long kj = ((unsigned long long)kb[j] << 32)
                            | (unsigned long long)(0xFFFFFFFFu - (unsigned)j);
#pragma unroll
      for (int t = 0; t < 8; t++) cnt[t] += (kj > ki64[t]) ? 1 : 0;
    }
  }
#pragma unroll
  for (int t = 0; t < 8; t++) {
    int i = i0 + t * 256;
    if (i < N_G && cnt[t] > 0) atomicAdd(&rank[b * N_G + i], cnt[t]);
  }
}

__global__ void scat_kernel(const int* __restrict__ rank, const float* __restrict__ score,
                            const float* __restrict__ d2a, const float* __restrict__ fcb,
                            float* __restrict__ z) {
  int b = blockIdx.y;
  int i = blockIdx.x * 256 + threadIdx.x;
  if (i < N_G) {
    int r = rank[b * N_G + i];
    if (r < K_TOP) z[b * K_TOP + r] = fmaf(score[b * N_G + i], d2a[b * N_G + i], fcb[0]);
  }
}

// ---------------- lin1: hpre[b][c] += sum_r z[b][r]*W[r][c] (r-split + atomics) ----------------
__global__ __launch_bounds__(256) void lin1_kernel(const float* __restrict__ z,
                                                   const float* __restrict__ W,
                                                   float* __restrict__ hpre) {
  __shared__ float zb[237];
  int b = blockIdx.y, rs = blockIdx.x;
  int r0 = rs * 237;
  int rn = K_TOP - r0; if (rn > 237) rn = 237;
  for (int q = threadIdx.x; q < rn; q += 256) zb[q] = z[b * K_TOP + r0 + q];
  __syncthreads();
  int c = threadIdx.x;
  float a0 = 0.f, a1 = 0.f;
  for (int r = 0; r < rn; ++r) {
    float zz = zb[r];
    const float* wr = W + (size_t)(r0 + r) * 512;
    a0 = fmaf(zz, wr[c], a0);
    a1 = fmaf(zz, wr[c + 256], a1);
  }
  atomicAdd(&hpre[b * 512 + c], a0);
  atomicAdd(&hpre[b * 512 + c + 256], a1);
}

// ---------------- lin2 + log_softmax ----------------
__global__ __launch_bounds__(128) void lin2_kernel(const float* __restrict__ hpre,
                                                   const float* __restrict__ l1b,
                                                   const float* __restrict__ W2,
                                                   const float* __restrict__ l2b,
                                                   float* __restrict__ out) {
  int b = blockIdx.x, tid = threadIdx.x;
  float a0 = 0.f, a1 = 0.f;
  for (int j = tid; j < 512; j += 128) {
    float t = fmaxf(hpre[b * 512 + j] + l1b[j], 0.f);
    a0 = fmaf(t, W2[j * 2 + 0], a0);
    a1 = fmaf(t, W2[j * 2 + 1], a1);
  }
#pragma unroll
  for (int s = 32; s > 0; s >>= 1) {
    a0 += __shfl_down(a0, s);
    a1 += __shfl_down(a1, s);
  }
  __shared__ float red[2][2];
  if ((tid & 63) == 0) { red[tid >> 6][0] = a0; red[tid >> 6][1] = a1; }
  __syncthreads();
  if (tid == 0) {
    float l0 = red[0][0] + red[1][0] + l2b[0];
    float l1 = red[0][1] + red[1][1] + l2b[1];
    float m = fmaxf(l0, l1);
    float lse = m + logf(expf(l0 - m) + expf(l1 - m));
    out[b * 2 + 0] = l0 - lse;
    out[b * 2 + 1] = l1 - lse;
  }
}

extern "C" void kernel_launch(void* const* d_in, const int* in_sizes, int n_in,
                              void* d_out, int out_size, void* d_ws, size_t ws_size,
                              hipStream_t stream) {
  const float* x   = (const float*)d_in[0];
  const int*   ei  = (const int*)d_in[2];
  const float* W1  = (const float*)d_in[3];
  const float* b1  = (const float*)d_in[4];
  const float* W2  = (const float*)d_in[5];
  const float* b2  = (const float*)d_in[6];
  const float* W3  = (const float*)d_in[7];
  const float* b3  = (const float*)d_in[8];
  const float* tkw = (const float*)d_in[9];
  const float* fcW = (const float*)d_in[10];
  const float* fcb = (const float*)d_in[11];
  const float* l1W = (const float*)d_in[12];
  const float* l1b = (const float*)d_in[13];
  const float* l2W = (const float*)d_in[14];
  const float* l2b = (const float*)d_in[15];
  float* out = (float*)d_out;

  char* ws = (char*)d_ws;
  size_t off = 0;
  auto alloc = [&](size_t bytes) {
    char* p = ws + off;
    off += (bytes + 255) & ~(size_t)255;
    return p;
  };
  // zero-init region (contiguous): cnt, fillc, gctr, rank, hpre
  int*   cnt   = (int*)alloc(15136 * 4);
  int*   fillc = (int*)alloc(15136 * 4);
  int*   gctr  = (int*)alloc(256);
  int*   rank  = (int*)alloc(121088 * 4);
  float* hpre  = (float*)alloc(4096 * 4);
  int*   rowstart = (int*)alloc(15136 * 4);
  float* dinv  = (float*)alloc(15136 * 4);
  float* scal  = (float*)alloc(64);
  float* z     = (float*)alloc((size_t)BSZ * K_TOP * 4);
  float* score = (float*)alloc(121088 * 4);
  float* d2a   = (float*)alloc(121088 * 4);
  unsigned* keys = (unsigned*)alloc(121088 * 4);
  int2*  csr   = (int2*)alloc((size_t)E_N * 8);
  float* hw = (float*)alloc((size_t)BSZ * N_G * NH * 4);
  float* h1 = (float*)alloc((size_t)BSZ * N_G * NH * 4);
  float* h2 = (float*)alloc((size_t)BSZ * N_G * NH * 4);
  (void)ws_size; (void)in_sizes; (void)n_in; (void)out_size;

  int zero_n = (int)(((char*)rowstart - (char*)cnt) / 4);
  zero_kernel<<<(zero_n + 1023) / 1024, 1024, 0, stream>>>(cnt, zero_n);
  count_kernel<<<(E_N + 255) / 256, 256, 0, stream>>>(ei, cnt);
  scan_kernel<<<(N_G + 1023) / 1024, 1024, 0, stream>>>(cnt, rowstart, dinv, gctr, tkw, scal);
  fill_kernel<<<(E_N + 255) / 256, 256, 0, stream>>>(ei, rowstart, dinv, fillc, csr);

  int M = BSZ * N_G;
  dim3 mmg((M + 63) / 64);
  int aggblocks = 8 * ((N_G + 3) / 4);

  mm_kernel<64><<<mmg, 256, 0, stream>>>(x, W1, hw, M);
  agg_kernel<<<aggblocks, 256, 0, stream>>>(hw, csr, rowstart, cnt, dinv, b1, h1);
  mm_kernel<128><<<mmg, 256, 0, stream>>>(h1, W2, hw, M);
  agg_kernel<<<aggblocks, 256, 0, stream>>>(hw, csr, rowstart, cnt, dinv, b2, h2);
  mm_kernel<128><<<mmg, 256, 0, stream>>>(h2, W3, hw, M);
  agg_score_kernel<<<aggblocks, 256, 0, stream>>>(hw, csr, rowstart, cnt, dinv, b3,
                                                  h1, h2, tkw, fcW, scal, keys, score, d2a);

  dim3 rg(8 * RANK_JS, BSZ);
  rank_kernel<<<rg, 256, 0, stream>>>(keys, rank);
  dim3 scg((N_G + 255) / 256, BSZ);
  scat_kernel<<<scg, 256, 0, stream>>>(rank, score, d2a, fcb, z);
  dim3 l1g(32, BSZ);
  lin1_kernel<<<l1g, 256, 0, stream>>>(z, l1W, hpre);
  lin2_kernel<<<BSZ, 128, 0, stream>>>(hpre, l1b, l2W, l2b, out);
}